// Round 1
// baseline (181.162 us; speedup 1.0000x reference)
//
#include <hip/hip_runtime.h>
#include <math.h>

// Problem constants
#define B_ 8
#define T_ 256
#define A_ 2
#define C_ 128
#define R_ 128
#define H_ 128
#define OUT_ 256

// Workspace layout (float offsets)
// pck  [C_*R_]   @ 0       : pos @ kW1[:R]
// pcv  [C_*R_]   @ 16384   : pos @ vW1[:R]
// psk  [B_*R_]   @ 32768   : session @ kW1[R:] + kb1
// psv  [B_*R_]   @ 33792   : session @ vW1[R:R+H] + vb1
// qk   [R_]      @ 34816   : kW2 @ query
// w    [B_*C_]   @ 34944   : softmax weights
#define WS_PCK 0
#define WS_PCV 16384
#define WS_PSK 32768
#define WS_PSV 33792
#define WS_QK  34816
#define WS_W   34944
#define WS_TOTAL 35968  // floats (~144 KB)

__device__ __forceinline__ float gelu_exact(float x) {
    return 0.5f * x * (1.0f + erff(x * 0.70710678118654752440f));
}

// ---------------------------------------------------------------------------
// Kernel 1: all the small projection dots into workspace.
// One thread per output element, 128-length dot each.
// ---------------------------------------------------------------------------
__global__ __launch_bounds__(256) void prep_kernel(
    const float* __restrict__ session,   // [B,H]
    const float* __restrict__ query,     // [R]
    const float* __restrict__ pos,       // [C,R]
    const float* __restrict__ kW1,       // [R+H, R]
    const float* __restrict__ kb1,       // [R]
    const float* __restrict__ kW2,       // [R, R]
    const float* __restrict__ vW1,       // [R+H+1, R]
    const float* __restrict__ vb1,       // [R]
    float* __restrict__ ws)
{
    const int g = blockIdx.x * 256 + threadIdx.x;
    if (g < 16384) {                       // pck[c][r] = pos[c,:] . kW1[:R][:,r]
        const int c = g >> 7, r = g & 127;
        float acc = 0.0f;
        #pragma unroll 8
        for (int k = 0; k < R_; ++k)
            acc += pos[c * R_ + k] * kW1[k * R_ + r];
        ws[WS_PCK + g] = acc;
    } else if (g < 32768) {                // pcv[c][r] = pos[c,:] . vW1[:R][:,r]
        const int e = g - 16384;
        const int c = e >> 7, r = e & 127;
        float acc = 0.0f;
        #pragma unroll 8
        for (int k = 0; k < R_; ++k)
            acc += pos[c * R_ + k] * vW1[k * R_ + r];
        ws[WS_PCV + e] = acc;
    } else if (g < 33792) {                // psk[b][r] = session[b,:] . kW1[R:][:,r] + kb1[r]
        const int e = g - 32768;
        const int b = e >> 7, r = e & 127;
        float acc = kb1[r];
        #pragma unroll 8
        for (int k = 0; k < H_; ++k)
            acc += session[b * H_ + k] * kW1[(R_ + k) * R_ + r];
        ws[WS_PSK + e] = acc;
    } else if (g < 34816) {                // psv[b][r] = session[b,:] . vW1[R:R+H][:,r] + vb1[r]
        const int e = g - 33792;
        const int b = e >> 7, r = e & 127;
        float acc = vb1[r];
        #pragma unroll 8
        for (int k = 0; k < H_; ++k)
            acc += session[b * H_ + k] * vW1[(R_ + k) * R_ + r];
        ws[WS_PSV + e] = acc;
    } else if (g < 34944) {                // qk[r] = kW2[r,:] . query
        const int r = g - 34816;
        float acc = 0.0f;
        #pragma unroll 8
        for (int j = 0; j < R_; ++j)
            acc += kW2[r * R_ + j] * query[j];
        ws[WS_QK + r] = acc;
    }
}

// ---------------------------------------------------------------------------
// Kernel 2: scores + softmax -> w[b][c].  8 blocks (one per b), 128 threads.
// scores[b,c] = gelu(pck[c,:] + psk[b,:]) . qk / sqrt(R)
// (kb2 . query is a constant shift over c -> cancels in softmax)
// ---------------------------------------------------------------------------
__global__ __launch_bounds__(128) void softmax_kernel(float* __restrict__ ws)
{
    __shared__ float red[128];
    const int b = blockIdx.x;
    const int c = threadIdx.x;
    const float* __restrict__ pck = ws + WS_PCK;
    const float* __restrict__ psk = ws + WS_PSK;
    const float* __restrict__ qk  = ws + WS_QK;

    float acc = 0.0f;
    #pragma unroll 4
    for (int r = 0; r < R_; ++r) {
        float x = pck[c * R_ + r] + psk[b * R_ + r];
        acc += gelu_exact(x) * qk[r];
    }
    const float score = acc * 0.08838834764831845f;  // 1/sqrt(128)

    red[c] = score;
    __syncthreads();
    for (int s = 64; s > 0; s >>= 1) {
        if (c < s) red[c] = fmaxf(red[c], red[c + s]);
        __syncthreads();
    }
    const float m = red[0];
    __syncthreads();
    const float e = expf(score - m);
    red[c] = e;
    __syncthreads();
    for (int s = 64; s > 0; s >>= 1) {
        if (c < s) red[c] += red[c + s];
        __syncthreads();
    }
    const float sum = red[0];
    ws[WS_W + b * C_ + c] = e / sum;
}

// ---------------------------------------------------------------------------
// Kernel 3: main. 512 blocks x 256 threads; each block does 8 (t,a) rows of
// one b.  p[j][r] = sum_c w[b,c]*gelu(comb[c,r] + s[j,c]*vrow[r]), then
// out[j][h] = p[j,:] @ vW2[:,h] + vb2[h].
// ---------------------------------------------------------------------------
__global__ __launch_bounds__(256) void main_kernel(
    const float* __restrict__ state,  // [B,T,A,C] = [B, 512, 128] rows
    const float* __restrict__ vW1,    // [R+H+1, R] ; last row = vrow
    const float* __restrict__ vW2,    // [R, OUT]
    const float* __restrict__ vb2,    // [OUT]
    const float* __restrict__ ws,
    float* __restrict__ out)          // [B,T,A,OUT]
{
    __shared__ float comb[C_ * R_];   // 64 KB: pcv[c][r] + psv[b][r] (+vb1 folded)
    __shared__ float sv[8 * C_];      // 4 KB : 8 state rows
    __shared__ float wv[C_];          // softmax weights for this b
    __shared__ float psvb[R_];
    __shared__ float p[8 * R_];       // 4 KB : weighted-gelu partials

    const int blk = blockIdx.x;
    const int b   = blk >> 6;    // / 64
    const int grp = blk & 63;
    const int tid = threadIdx.x;

    const float* __restrict__ pcv = ws + WS_PCV;
    const float* __restrict__ psv = ws + WS_PSV;
    const float* __restrict__ wb  = ws + WS_W + b * C_;

    if (tid < 128) {
        psvb[tid] = psv[b * R_ + tid];
        wv[tid]   = wb[tid];
    }
    const float* __restrict__ srow = state + (size_t)(b * 512 + grp * 8) * C_;
    for (int i = tid; i < 8 * C_; i += 256) sv[i] = srow[i];
    __syncthreads();

    for (int i = tid; i < C_ * R_; i += 256) comb[i] = pcv[i] + psvb[i & 127];
    __syncthreads();

    const int r    = tid & 127;
    const int half = tid >> 7;
    const float vr = vW1[(R_ + H_) * R_ + r];   // vW1 last row, element r

    float acc[8];
    #pragma unroll
    for (int j = 0; j < 8; ++j) acc[j] = 0.0f;

    const int c0 = half * 64;
    for (int c = c0; c < c0 + 64; ++c) {
        const float cc = comb[c * R_ + r];
        const float wc = wv[c];
        #pragma unroll
        for (int j = 0; j < 8; ++j) {
            const float x = cc + sv[j * C_ + c] * vr;
            acc[j] += wc * gelu_exact(x);
        }
    }

    if (half == 0) {
        #pragma unroll
        for (int j = 0; j < 8; ++j) p[j * R_ + r] = acc[j];
    }
    __syncthreads();
    if (half == 1) {
        #pragma unroll
        for (int j = 0; j < 8; ++j) p[j * R_ + r] += acc[j];
    }
    __syncthreads();

    // Epilogue: out[j][h] = p[j,:] @ vW2[:,h] + vb2[h], h = tid
    const int h = tid;
    float o[8];
    const float bias = vb2[h];
    #pragma unroll
    for (int j = 0; j < 8; ++j) o[j] = bias;
    for (int rr = 0; rr < R_; ++rr) {
        const float wcol = vW2[rr * OUT_ + h];
        #pragma unroll
        for (int j = 0; j < 8; ++j) o[j] += p[j * R_ + rr] * wcol;
    }
    float* __restrict__ orow = out + (size_t)(b * 512 + grp * 8) * OUT_;
    #pragma unroll
    for (int j = 0; j < 8; ++j) orow[j * OUT_ + h] = o[j];
}

extern "C" void kernel_launch(void* const* d_in, const int* in_sizes, int n_in,
                              void* d_out, int out_size, void* d_ws, size_t ws_size,
                              hipStream_t stream) {
    const float* state   = (const float*)d_in[0];   // [B,T,A,C]
    const float* session = (const float*)d_in[1];   // [B,H]
    // d_in[2] subject, d_in[3] array : unused by the reference math
    const float* query   = (const float*)d_in[4];   // [R]
    const float* pos     = (const float*)d_in[5];   // [C,R]
    const float* kW1     = (const float*)d_in[6];   // [R+H, R]
    const float* kb1     = (const float*)d_in[7];   // [R]
    const float* kW2     = (const float*)d_in[8];   // [R, R]
    // d_in[9] kb2 : constant shift in scores, cancels in softmax
    const float* vW1     = (const float*)d_in[10];  // [R+H+1, R]
    const float* vb1     = (const float*)d_in[11];  // [R]
    const float* vW2     = (const float*)d_in[12];  // [R, OUT]
    const float* vb2     = (const float*)d_in[13];  // [OUT]

    float* ws  = (float*)d_ws;
    float* out = (float*)d_out;

    // Kernel 1: 34944 elements, 256 thr/blk
    prep_kernel<<<137, 256, 0, stream>>>(session, query, pos, kW1, kb1, kW2,
                                         vW1, vb1, ws);
    // Kernel 2: softmax weights
    softmax_kernel<<<B_, 128, 0, stream>>>(ws);
    // Kernel 3: main
    main_kernel<<<B_ * 64, 256, 0, stream>>>(state, vW1, vW2, vb2, ws, out);
}

// Round 2
// 133.445 us; speedup vs baseline: 1.3576x; 1.3576x over previous
//
#include <hip/hip_runtime.h>
#include <math.h>

// Problem constants
#define B_ 8
#define T_ 256
#define A_ 2
#define C_ 128
#define R_ 128
#define H_ 128
#define OUT_ 256

// Workspace layout (float offsets)
#define WS_PCK 0
#define WS_PCV 16384
#define WS_PSK 32768
#define WS_PSV 33792
#define WS_QK  34816
#define WS_W   34944
#define WS_TOTAL 35968  // floats (~144 KB)

// Branchless fast gelu: 0.5x(1+erf(x/sqrt(2))) via Abramowitz-Stegun 7.1.26
// (|erf err| <= ~1.5e-7).  ~18 VALU ops, 1 v_rcp + 1 v_exp, no branches.
__device__ __forceinline__ float gelu_fast(float x) {
    const float z  = x * 0.70710678118654752440f;
    const float az = fabsf(z);
    const float t  = __builtin_amdgcn_rcpf(fmaf(0.3275911f, az, 1.0f));
    const float em = __expf(-az * az);
    float p = fmaf(1.061405429f, t, -1.453152027f);
    p = fmaf(p, t, 1.421413741f);
    p = fmaf(p, t, -0.284496736f);
    p = fmaf(p, t, 0.254829592f);
    p = p * t;
    const float er = fmaf(-p, em, 1.0f);               // erf(az) >= 0
    // gelu = 0.5x + 0.5|x|*er = 0.5x + (sqrt(2)/2)*az*er
    return fmaf(0.70710678118654752440f * er, az, 0.5f * x);
}

// ---------------------------------------------------------------------------
// Kernel 1: small projection dots into workspace (unchanged).
// ---------------------------------------------------------------------------
__global__ __launch_bounds__(256) void prep_kernel(
    const float* __restrict__ session,   // [B,H]
    const float* __restrict__ query,     // [R]
    const float* __restrict__ pos,       // [C,R]
    const float* __restrict__ kW1,       // [R+H, R]
    const float* __restrict__ kb1,       // [R]
    const float* __restrict__ kW2,       // [R, R]
    const float* __restrict__ vW1,       // [R+H+1, R]
    const float* __restrict__ vb1,       // [R]
    float* __restrict__ ws)
{
    const int g = blockIdx.x * 256 + threadIdx.x;
    if (g < 16384) {
        const int c = g >> 7, r = g & 127;
        float acc = 0.0f;
        #pragma unroll 8
        for (int k = 0; k < R_; ++k)
            acc += pos[c * R_ + k] * kW1[k * R_ + r];
        ws[WS_PCK + g] = acc;
    } else if (g < 32768) {
        const int e = g - 16384;
        const int c = e >> 7, r = e & 127;
        float acc = 0.0f;
        #pragma unroll 8
        for (int k = 0; k < R_; ++k)
            acc += pos[c * R_ + k] * vW1[k * R_ + r];
        ws[WS_PCV + e] = acc;
    } else if (g < 33792) {
        const int e = g - 32768;
        const int b = e >> 7, r = e & 127;
        float acc = kb1[r];
        #pragma unroll 8
        for (int k = 0; k < H_; ++k)
            acc += session[b * H_ + k] * kW1[(R_ + k) * R_ + r];
        ws[WS_PSK + e] = acc;
    } else if (g < 34816) {
        const int e = g - 33792;
        const int b = e >> 7, r = e & 127;
        float acc = vb1[r];
        #pragma unroll 8
        for (int k = 0; k < H_; ++k)
            acc += session[b * H_ + k] * vW1[(R_ + k) * R_ + r];
        ws[WS_PSV + e] = acc;
    } else if (g < 34944) {
        const int r = g - 34816;
        float acc = 0.0f;
        #pragma unroll 8
        for (int j = 0; j < R_; ++j)
            acc += kW2[r * R_ + j] * query[j];
        ws[WS_QK + r] = acc;
    }
}

// ---------------------------------------------------------------------------
// Kernel 2: scores + softmax -> w[b][c].  8 blocks, 128 threads.
// ---------------------------------------------------------------------------
__global__ __launch_bounds__(128) void softmax_kernel(float* __restrict__ ws)
{
    __shared__ float red[128];
    const int b = blockIdx.x;
    const int c = threadIdx.x;
    const float* __restrict__ pck = ws + WS_PCK;
    const float* __restrict__ psk = ws + WS_PSK;
    const float* __restrict__ qk  = ws + WS_QK;

    float acc = 0.0f;
    #pragma unroll 4
    for (int r = 0; r < R_; ++r) {
        float x = pck[c * R_ + r] + psk[b * R_ + r];
        acc += gelu_fast(x) * qk[r];
    }
    const float score = acc * 0.08838834764831845f;  // 1/sqrt(128)

    red[c] = score;
    __syncthreads();
    for (int s = 64; s > 0; s >>= 1) {
        if (c < s) red[c] = fmaxf(red[c], red[c + s]);
        __syncthreads();
    }
    const float m = red[0];
    __syncthreads();
    const float e = __expf(score - m);
    red[c] = e;
    __syncthreads();
    for (int s = 64; s > 0; s >>= 1) {
        if (c < s) red[c] += red[c + s];
        __syncthreads();
    }
    const float sum = red[0];
    ws[WS_W + b * C_ + c] = e / sum;
}

// ---------------------------------------------------------------------------
// Kernel 3: main. 1024 blocks x 256 threads; each block: 4 (t,a) rows of one
// b.  Thread (half, r): c in [half*64, +64), 4 independent gelu chains.
// pcv read straight from L2 (no 64KB LDS stage) -> ~9KB LDS, 4 blocks/CU.
// ---------------------------------------------------------------------------
__global__ __launch_bounds__(256) void main_kernel(
    const float* __restrict__ state,  // [B, 512, 128] rows
    const float* __restrict__ vW1,    // [R+H+1, R] ; last row = vrow
    const float* __restrict__ vW2,    // [R, OUT]
    const float* __restrict__ vb2,    // [OUT]
    const float* __restrict__ ws,
    float* __restrict__ out)          // [B, 512, OUT]
{
    __shared__ float sv[4 * C_];      // 2 KB : 4 state rows
    __shared__ float wv[C_];          // softmax weights for this b
    __shared__ float p[4 * R_];       // 2 KB : weighted-gelu partials

    const int blk  = blockIdx.x;
    const int b    = blk >> 7;        // / 128
    const int grp  = blk & 127;
    const int tid  = threadIdx.x;
    const int r    = tid & 127;
    const int half = tid >> 7;

    const float* __restrict__ pcv = ws + WS_PCV;

    if (tid < 128) wv[tid] = ws[WS_W + b * C_ + tid];
    const float* __restrict__ srow = state + (size_t)(b * 512 + grp * 4) * C_;
    for (int i = tid; i < 4 * C_; i += 256) sv[i] = srow[i];

    const float vr    = vW1[(R_ + H_) * R_ + r];   // vW1 last row, element r
    const float psv_r = ws[WS_PSV + b * R_ + r];
    __syncthreads();

    float acc0 = 0.0f, acc1 = 0.0f, acc2 = 0.0f, acc3 = 0.0f;
    const int c0 = half * 64;
    const float* __restrict__ pcvr = pcv + r;
    #pragma unroll 4
    for (int c = c0; c < c0 + 64; ++c) {
        const float cc = pcvr[c * R_] + psv_r;
        const float wc = wv[c];
        const float x0 = fmaf(sv[0 * C_ + c], vr, cc);
        const float x1 = fmaf(sv[1 * C_ + c], vr, cc);
        const float x2 = fmaf(sv[2 * C_ + c], vr, cc);
        const float x3 = fmaf(sv[3 * C_ + c], vr, cc);
        acc0 = fmaf(wc, gelu_fast(x0), acc0);
        acc1 = fmaf(wc, gelu_fast(x1), acc1);
        acc2 = fmaf(wc, gelu_fast(x2), acc2);
        acc3 = fmaf(wc, gelu_fast(x3), acc3);
    }

    if (half == 0) {
        p[0 * R_ + r] = acc0;
        p[1 * R_ + r] = acc1;
        p[2 * R_ + r] = acc2;
        p[3 * R_ + r] = acc3;
    }
    __syncthreads();
    if (half == 1) {
        p[0 * R_ + r] += acc0;
        p[1 * R_ + r] += acc1;
        p[2 * R_ + r] += acc2;
        p[3 * R_ + r] += acc3;
    }
    __syncthreads();

    // Epilogue: out[j][h] = p[j,:] @ vW2[:,h] + vb2[h], h = tid
    const int h = tid;
    const float bias = vb2[h];
    float o0 = bias, o1 = bias, o2 = bias, o3 = bias;
    #pragma unroll 8
    for (int rr = 0; rr < R_; ++rr) {
        const float wcol = vW2[rr * OUT_ + h];
        o0 = fmaf(p[0 * R_ + rr], wcol, o0);
        o1 = fmaf(p[1 * R_ + rr], wcol, o1);
        o2 = fmaf(p[2 * R_ + rr], wcol, o2);
        o3 = fmaf(p[3 * R_ + rr], wcol, o3);
    }
    float* __restrict__ orow = out + (size_t)(b * 512 + grp * 4) * OUT_;
    orow[0 * OUT_ + h] = o0;
    orow[1 * OUT_ + h] = o1;
    orow[2 * OUT_ + h] = o2;
    orow[3 * OUT_ + h] = o3;
}

extern "C" void kernel_launch(void* const* d_in, const int* in_sizes, int n_in,
                              void* d_out, int out_size, void* d_ws, size_t ws_size,
                              hipStream_t stream) {
    const float* state   = (const float*)d_in[0];   // [B,T,A,C]
    const float* session = (const float*)d_in[1];   // [B,H]
    const float* query   = (const float*)d_in[4];   // [R]
    const float* pos     = (const float*)d_in[5];   // [C,R]
    const float* kW1     = (const float*)d_in[6];   // [R+H, R]
    const float* kb1     = (const float*)d_in[7];   // [R]
    const float* kW2     = (const float*)d_in[8];   // [R, R]
    const float* vW1     = (const float*)d_in[10];  // [R+H+1, R]
    const float* vb1     = (const float*)d_in[11];  // [R]
    const float* vW2     = (const float*)d_in[12];  // [R, OUT]
    const float* vb2     = (const float*)d_in[13];  // [OUT]

    float* ws  = (float*)d_ws;
    float* out = (float*)d_out;

    prep_kernel<<<137, 256, 0, stream>>>(session, query, pos, kW1, kb1, kW2,
                                         vW1, vb1, ws);
    softmax_kernel<<<B_, 128, 0, stream>>>(ws);
    main_kernel<<<B_ * 128, 256, 0, stream>>>(state, vW1, vW2, vb2, ws, out);
}

// Round 4
// 126.905 us; speedup vs baseline: 1.4275x; 1.0515x over previous
//
#include <hip/hip_runtime.h>
#include <math.h>

// Problem constants
#define B_ 8
#define T_ 256
#define A_ 2
#define C_ 128
#define R_ 128
#define H_ 128
#define OUT_ 256

// Workspace layout (float offsets)
#define WS_PCK 0
#define WS_PCV 16384
#define WS_PSK 32768
#define WS_PSV 33792
#define WS_QK  34816
#define WS_W   34944
#define WS_TOTAL 35968  // floats (~144 KB)

// Branchless fast gelu via Abramowitz-Stegun 7.1.26 (|erf err| <= ~1.5e-7).
// 13 full-rate VALU + 1 v_rcp + 1 v_exp, no branches.
__device__ __forceinline__ float gelu_fast(float x) {
    const float ax = fabsf(x);
    const float az = 0.70710678118654752440f * ax;
    const float t  = __builtin_amdgcn_rcpf(fmaf(0.3275911f, az, 1.0f));
    const float em = __expf(-az * az);
    float p = fmaf(1.061405429f, t, -1.453152027f);
    p = fmaf(p, t, 1.421413741f);
    p = fmaf(p, t, -0.284496736f);
    p = fmaf(p, t, 0.254829592f);
    p = p * t;
    const float er = fmaf(-p, em, 1.0f);               // erf(az) >= 0
    return fmaf(er, 0.70710678118654752440f * az, 0.5f * x);
}

// ---------------------------------------------------------------------------
// Kernel 1: small projection dots into workspace.
// ---------------------------------------------------------------------------
__global__ __launch_bounds__(256) void prep_kernel(
    const float* __restrict__ session,   // [B,H]
    const float* __restrict__ query,     // [R]
    const float* __restrict__ pos,       // [C,R]
    const float* __restrict__ kW1,       // [R+H, R]
    const float* __restrict__ kb1,       // [R]
    const float* __restrict__ kW2,       // [R, R]
    const float* __restrict__ vW1,       // [R+H+1, R]
    const float* __restrict__ vb1,       // [R]
    float* __restrict__ ws)
{
    const int g = blockIdx.x * 256 + threadIdx.x;
    if (g < 16384) {                       // pck[c][r]
        const int c = g >> 7, r = g & 127;
        float acc = 0.0f;
        #pragma unroll 16
        for (int k = 0; k < R_; ++k)
            acc += pos[c * R_ + k] * kW1[k * R_ + r];
        ws[WS_PCK + g] = acc;
    } else if (g < 32768) {                // pcv[c][r]
        const int e = g - 16384;
        const int c = e >> 7, r = e & 127;
        float acc = 0.0f;
        #pragma unroll 16
        for (int k = 0; k < R_; ++k)
            acc += pos[c * R_ + k] * vW1[k * R_ + r];
        ws[WS_PCV + e] = acc;
    } else if (g < 33792) {                // psk[b][r] (+kb1)
        const int e = g - 32768;
        const int b = e >> 7, r = e & 127;
        float acc = kb1[r];
        #pragma unroll 16
        for (int k = 0; k < H_; ++k)
            acc += session[b * H_ + k] * kW1[(R_ + k) * R_ + r];
        ws[WS_PSK + e] = acc;
    } else if (g < 34816) {                // psv[b][r] (+vb1)
        const int e = g - 33792;
        const int b = e >> 7, r = e & 127;
        float acc = vb1[r];
        #pragma unroll 16
        for (int k = 0; k < H_; ++k)
            acc += session[b * H_ + k] * vW1[(R_ + k) * R_ + r];
        ws[WS_PSV + e] = acc;
    } else if (g < 34944) {                // qk[r] = kW2[r,:] . query
        const int r = g - 34816;
        float acc = 0.0f;
        #pragma unroll 16
        for (int j = 0; j < R_; ++j)
            acc += kW2[r * R_ + j] * query[j];
        ws[WS_QK + r] = acc;
    }
}

// ---------------------------------------------------------------------------
// Kernel 2: scores + softmax, wide.  8 blocks x 512 threads.
// Thread (q = tid>>7, c = tid&127): partial gelu-dot over r in [32q, 32q+32),
// LDS-combine the 4 partials, then in-block softmax over the 128 scores.
// ---------------------------------------------------------------------------
__global__ __launch_bounds__(512) void score_softmax_kernel(float* __restrict__ ws)
{
    __shared__ float pskL[R_];
    __shared__ float qkL[R_];
    __shared__ float part[4][C_];
    __shared__ float sc[C_];
    __shared__ float red[C_];

    const int b   = blockIdx.x;
    const int tid = threadIdx.x;
    const int q   = tid >> 7;
    const int c   = tid & 127;

    if (tid < 128) {
        pskL[tid] = ws[WS_PSK + b * R_ + tid];
        qkL[tid]  = ws[WS_QK + tid];
    }
    __syncthreads();

    const float* __restrict__ pckc = ws + WS_PCK + c * R_ + q * 32;
    float acc = 0.0f;
    #pragma unroll 8
    for (int i = 0; i < 32; ++i) {
        const float x = pckc[i] + pskL[q * 32 + i];
        acc += gelu_fast(x) * qkL[q * 32 + i];
    }
    part[q][c] = acc;
    __syncthreads();

    if (tid < 128) {
        const float s = (part[0][tid] + part[1][tid] + part[2][tid] + part[3][tid])
                        * 0.08838834764831845f;  // 1/sqrt(128)
        sc[tid]  = s;
        red[tid] = s;
    }
    __syncthreads();
    for (int st = 64; st > 0; st >>= 1) {
        if (tid < st) red[tid] = fmaxf(red[tid], red[tid + st]);
        __syncthreads();
    }
    const float m = red[0];
    __syncthreads();
    if (tid < 128) {
        const float e = __expf(sc[tid] - m);
        sc[tid]  = e;
        red[tid] = e;
    }
    __syncthreads();
    for (int st = 64; st > 0; st >>= 1) {
        if (tid < st) red[tid] += red[tid + st];
        __syncthreads();
    }
    if (tid < 128) ws[WS_W + b * C_ + tid] = sc[tid] / red[0];
}

// ---------------------------------------------------------------------------
// Kernel 3: main. 2048 blocks x 256 threads; 2 (t,a) rows per block.
// Thread (half = tid>>7, r = tid&127): c in [half*64, +64), 2 gelu chains.
// NO min-waves clamp: R3's (256,8) forced VGPR<=64 -> spills -> graph-capture
// abort. Natural allocation (~44 VGPR in R2) already allows 8 waves/SIMD.
// ---------------------------------------------------------------------------
__global__ __launch_bounds__(256) void main_kernel(
    const float* __restrict__ state,  // [B, 512, 128] rows
    const float* __restrict__ vW1,    // [R+H+1, R] ; last row = vrow
    const float* __restrict__ vW2,    // [R, OUT]
    const float* __restrict__ vb2,    // [OUT]
    const float* __restrict__ ws,
    float* __restrict__ out)          // [B, 512, OUT]
{
    __shared__ float  sv[2 * C_];     // 2 state rows
    __shared__ float  wv[C_];         // softmax weights for this b
    __shared__ float2 p2[R_];         // weighted-gelu partials, [r] -> (row0,row1)

    const int blk  = blockIdx.x;
    const int b    = blk >> 8;        // / 256
    const int grp  = blk & 255;
    const int tid  = threadIdx.x;
    const int r    = tid & 127;
    const int half = tid >> 7;

    if (tid < 128) wv[tid] = ws[WS_W + b * C_ + tid];
    const float* __restrict__ srow = state + (size_t)(b * 512 + grp * 2) * C_;
    sv[tid] = srow[tid];              // 256 threads == 2*C_ elements

    const float vr    = vW1[(R_ + H_) * R_ + r];   // vW1 last row, element r
    const float psv_r = ws[WS_PSV + b * R_ + r];
    __syncthreads();

    float acc0 = 0.0f, acc1 = 0.0f;
    const int c0 = half * 64;
    const float* __restrict__ pcvr = ws + WS_PCV + r;
    #pragma unroll 4
    for (int c = c0; c < c0 + 64; ++c) {
        const float cc = pcvr[c * R_] + psv_r;
        const float wc = wv[c];
        const float x0 = fmaf(sv[c], vr, cc);
        const float x1 = fmaf(sv[C_ + c], vr, cc);
        acc0 = fmaf(wc, gelu_fast(x0), acc0);
        acc1 = fmaf(wc, gelu_fast(x1), acc1);
    }

    if (half == 0) p2[r] = make_float2(acc0, acc1);
    __syncthreads();
    if (half == 1) {
        float2 t = p2[r];
        t.x += acc0; t.y += acc1;
        p2[r] = t;
    }
    __syncthreads();

    // Epilogue: out[j][h] = p[j,:] @ vW2[:,h] + vb2[h], h = tid
    const int h = tid;
    const float bias = vb2[h];
    float o0 = bias, o1 = bias;
    #pragma unroll 8
    for (int rr = 0; rr < R_; ++rr) {
        const float wcol = vW2[rr * OUT_ + h];
        const float2 pr = p2[rr];     // one ds_read_b64 broadcast
        o0 = fmaf(pr.x, wcol, o0);
        o1 = fmaf(pr.y, wcol, o1);
    }
    float* __restrict__ orow = out + (size_t)(b * 512 + grp * 2) * OUT_;
    orow[h]        = o0;
    orow[OUT_ + h] = o1;
}

extern "C" void kernel_launch(void* const* d_in, const int* in_sizes, int n_in,
                              void* d_out, int out_size, void* d_ws, size_t ws_size,
                              hipStream_t stream) {
    const float* state   = (const float*)d_in[0];   // [B,T,A,C]
    const float* session = (const float*)d_in[1];   // [B,H]
    const float* query   = (const float*)d_in[4];   // [R]
    const float* pos     = (const float*)d_in[5];   // [C,R]
    const float* kW1     = (const float*)d_in[6];   // [R+H, R]
    const float* kb1     = (const float*)d_in[7];   // [R]
    const float* kW2     = (const float*)d_in[8];   // [R, R]
    const float* vW1     = (const float*)d_in[10];  // [R+H+1, R]
    const float* vb1     = (const float*)d_in[11];  // [R]
    const float* vW2     = (const float*)d_in[12];  // [R, OUT]
    const float* vb2     = (const float*)d_in[13];  // [OUT]

    float* ws  = (float*)d_ws;
    float* out = (float*)d_out;

    prep_kernel<<<137, 256, 0, stream>>>(session, query, pos, kW1, kb1, kW2,
                                         vW1, vb1, ws);
    score_softmax_kernel<<<B_, 512, 0, stream>>>(ws);
    main_kernel<<<B_ * 256, 256, 0, stream>>>(state, vW1, vW2, vb2, ws, out);
}

// Round 5
// 117.578 us; speedup vs baseline: 1.5408x; 1.0793x over previous
//
#include <hip/hip_runtime.h>
#include <math.h>

// Problem constants
#define B_ 8
#define T_ 256
#define A_ 2
#define C_ 128
#define R_ 128
#define H_ 128
#define OUT_ 256

// Workspace layout (float offsets)
#define WS_PCK 0
#define WS_PCV 16384
#define WS_PSK 32768
#define WS_PSV 33792
#define WS_QK  34816
#define WS_W   34944
#define WS_TOTAL 35968  // floats (~144 KB)

// gelu via A&S 7.1.27: erf(z) ~ 1 - (1 + a1 z + a2 z^2 + a3 z^3 + a4 z^4)^-4,
// z >= 0, |err| <= 5e-4.  sqrt(1/2) folded into coefficients so z = |x| works:
//   b_k = a_k * (1/sqrt(2))^k
// gelu(x) = 0.5x(1+erf(x/sqrt2)) = max(x,0) - 0.5|x| * q^-4.
// 9 full-rate VALU + 1 v_rcp, NO exp, branchless.
__device__ __forceinline__ float gelu_fast(float x) {
    const float ax = fabsf(x);
    float q = fmaf(ax, 0.019527f, 0.000343654f);   // b4, b3
    q = fmaf(q, ax, 0.1151945f);                   // b2
    q = fmaf(q, ax, 0.19685217f);                  // b1
    q = fmaf(q, ax, 1.0f);
    const float r  = __builtin_amdgcn_rcpf(q);
    const float r2 = r * r;
    const float r4 = r2 * r2;
    return fmaf(-0.5f * ax, r4, fmaxf(x, 0.0f));
}

// ---------------------------------------------------------------------------
// Kernel 1: small projection dots into workspace.
// ---------------------------------------------------------------------------
__global__ __launch_bounds__(256) void prep_kernel(
    const float* __restrict__ session,   // [B,H]
    const float* __restrict__ query,     // [R]
    const float* __restrict__ pos,       // [C,R]
    const float* __restrict__ kW1,       // [R+H, R]
    const float* __restrict__ kb1,       // [R]
    const float* __restrict__ kW2,       // [R, R]
    const float* __restrict__ vW1,       // [R+H+1, R]
    const float* __restrict__ vb1,       // [R]
    float* __restrict__ ws)
{
    const int g = blockIdx.x * 256 + threadIdx.x;
    if (g < 16384) {                       // pck[c][r]
        const int c = g >> 7, r = g & 127;
        float acc = 0.0f;
        #pragma unroll 16
        for (int k = 0; k < R_; ++k)
            acc += pos[c * R_ + k] * kW1[k * R_ + r];
        ws[WS_PCK + g] = acc;
    } else if (g < 32768) {                // pcv[c][r]
        const int e = g - 16384;
        const int c = e >> 7, r = e & 127;
        float acc = 0.0f;
        #pragma unroll 16
        for (int k = 0; k < R_; ++k)
            acc += pos[c * R_ + k] * vW1[k * R_ + r];
        ws[WS_PCV + e] = acc;
    } else if (g < 33792) {                // psk[b][r] (+kb1)
        const int e = g - 32768;
        const int b = e >> 7, r = e & 127;
        float acc = kb1[r];
        #pragma unroll 16
        for (int k = 0; k < H_; ++k)
            acc += session[b * H_ + k] * kW1[(R_ + k) * R_ + r];
        ws[WS_PSK + e] = acc;
    } else if (g < 34816) {                // psv[b][r] (+vb1)
        const int e = g - 33792;
        const int b = e >> 7, r = e & 127;
        float acc = vb1[r];
        #pragma unroll 16
        for (int k = 0; k < H_; ++k)
            acc += session[b * H_ + k] * vW1[(R_ + k) * R_ + r];
        ws[WS_PSV + e] = acc;
    } else if (g < 34944) {                // qk[r] = kW2[r,:] . query
        const int r = g - 34816;
        float acc = 0.0f;
        #pragma unroll 16
        for (int j = 0; j < R_; ++j)
            acc += kW2[r * R_ + j] * query[j];
        ws[WS_QK + r] = acc;
    }
}

// ---------------------------------------------------------------------------
// Kernel 2: scores + softmax, wide.  8 blocks x 512 threads.
// ---------------------------------------------------------------------------
__global__ __launch_bounds__(512) void score_softmax_kernel(float* __restrict__ ws)
{
    __shared__ float pskL[R_];
    __shared__ float qkL[R_];
    __shared__ float part[4][C_];
    __shared__ float sc[C_];
    __shared__ float red[C_];

    const int b   = blockIdx.x;
    const int tid = threadIdx.x;
    const int q   = tid >> 7;
    const int c   = tid & 127;

    if (tid < 128) {
        pskL[tid] = ws[WS_PSK + b * R_ + tid];
        qkL[tid]  = ws[WS_QK + tid];
    }
    __syncthreads();

    const float* __restrict__ pckc = ws + WS_PCK + c * R_ + q * 32;
    float acc = 0.0f;
    #pragma unroll 8
    for (int i = 0; i < 32; ++i) {
        const float x = pckc[i] + pskL[q * 32 + i];
        acc += gelu_fast(x) * qkL[q * 32 + i];
    }
    part[q][c] = acc;
    __syncthreads();

    if (tid < 128) {
        const float s = (part[0][tid] + part[1][tid] + part[2][tid] + part[3][tid])
                        * 0.08838834764831845f;  // 1/sqrt(128)
        sc[tid]  = s;
        red[tid] = s;
    }
    __syncthreads();
    for (int st = 64; st > 0; st >>= 1) {
        if (tid < st) red[tid] = fmaxf(red[tid], red[tid + st]);
        __syncthreads();
    }
    const float m = red[0];
    __syncthreads();
    if (tid < 128) {
        const float e = __expf(sc[tid] - m);
        sc[tid]  = e;
        red[tid] = e;
    }
    __syncthreads();
    for (int st = 64; st > 0; st >>= 1) {
        if (tid < st) red[tid] += red[tid + st];
        __syncthreads();
    }
    if (tid < 128) ws[WS_W + b * C_ + tid] = sc[tid] / red[0];
}

// ---------------------------------------------------------------------------
// Kernel 3: main. 2048 blocks x 256 threads; 2 (t,a) rows per block.
// Thread (half = tid>>7, r = tid&127): c in [half*64, +64), 2 gelu chains.
// ---------------------------------------------------------------------------
__global__ __launch_bounds__(256) void main_kernel(
    const float* __restrict__ state,  // [B, 512, 128] rows
    const float* __restrict__ vW1,    // [R+H+1, R] ; last row = vrow
    const float* __restrict__ vW2,    // [R, OUT]
    const float* __restrict__ vb2,    // [OUT]
    const float* __restrict__ ws,
    float* __restrict__ out)          // [B, 512, OUT]
{
    __shared__ float  sv[2 * C_];     // 2 state rows
    __shared__ float  wv[C_];         // softmax weights for this b
    __shared__ float2 p2[R_];         // weighted-gelu partials, [r] -> (row0,row1)

    const int blk  = blockIdx.x;
    const int b    = blk >> 8;        // / 256
    const int grp  = blk & 255;
    const int tid  = threadIdx.x;
    const int r    = tid & 127;
    const int half = tid >> 7;

    if (tid < 128) wv[tid] = ws[WS_W + b * C_ + tid];
    const float* __restrict__ srow = state + (size_t)(b * 512 + grp * 2) * C_;
    sv[tid] = srow[tid];              // 256 threads == 2*C_ elements

    const float vr    = vW1[(R_ + H_) * R_ + r];   // vW1 last row, element r
    const float psv_r = ws[WS_PSV + b * R_ + r];
    __syncthreads();

    float acc0 = 0.0f, acc1 = 0.0f;
    const int c0 = half * 64;
    const float* __restrict__ pcvr = ws + WS_PCV + r;
    #pragma unroll 8
    for (int c = c0; c < c0 + 64; ++c) {
        const float cc = pcvr[c * R_] + psv_r;
        const float wc = wv[c];
        const float x0 = fmaf(sv[c], vr, cc);
        const float x1 = fmaf(sv[C_ + c], vr, cc);
        acc0 = fmaf(wc, gelu_fast(x0), acc0);
        acc1 = fmaf(wc, gelu_fast(x1), acc1);
    }

    if (half == 0) p2[r] = make_float2(acc0, acc1);
    __syncthreads();
    if (half == 1) {
        float2 t = p2[r];
        t.x += acc0; t.y += acc1;
        p2[r] = t;
    }
    __syncthreads();

    // Epilogue: out[j][h] = p[j,:] @ vW2[:,h] + vb2[h], h = tid
    const int h = tid;
    const float bias = vb2[h];
    float o0 = bias, o1 = bias;
    #pragma unroll 16
    for (int rr = 0; rr < R_; ++rr) {
        const float wcol = vW2[rr * OUT_ + h];
        const float2 pr = p2[rr];     // one ds_read_b64 broadcast
        o0 = fmaf(pr.x, wcol, o0);
        o1 = fmaf(pr.y, wcol, o1);
    }
    float* __restrict__ orow = out + (size_t)(b * 512 + grp * 2) * OUT_;
    orow[h]        = o0;
    orow[OUT_ + h] = o1;
}

extern "C" void kernel_launch(void* const* d_in, const int* in_sizes, int n_in,
                              void* d_out, int out_size, void* d_ws, size_t ws_size,
                              hipStream_t stream) {
    const float* state   = (const float*)d_in[0];   // [B,T,A,C]
    const float* session = (const float*)d_in[1];   // [B,H]
    const float* query   = (const float*)d_in[4];   // [R]
    const float* pos     = (const float*)d_in[5];   // [C,R]
    const float* kW1     = (const float*)d_in[6];   // [R+H, R]
    const float* kb1     = (const float*)d_in[7];   // [R]
    const float* kW2     = (const float*)d_in[8];   // [R, R]
    const float* vW1     = (const float*)d_in[10];  // [R+H+1, R]
    const float* vb1     = (const float*)d_in[11];  // [R]
    const float* vW2     = (const float*)d_in[12];  // [R, OUT]
    const float* vb2     = (const float*)d_in[13];  // [OUT]

    float* ws  = (float*)d_ws;
    float* out = (float*)d_out;

    prep_kernel<<<137, 256, 0, stream>>>(session, query, pos, kW1, kb1, kW2,
                                         vW1, vb1, ws);
    score_softmax_kernel<<<B_, 512, 0, stream>>>(ws);
    main_kernel<<<B_ * 256, 256, 0, stream>>>(state, vW1, vW2, vb2, ws, out);
}